// Round 1
// baseline (379.538 us; speedup 1.0000x reference)
//
#include <hip/hip_runtime.h>
#include <hip/hip_bf16.h>

typedef __bf16 bf16_t;
typedef __attribute__((ext_vector_type(8))) __bf16 bf16x8;
typedef __attribute__((ext_vector_type(4))) float f32x4;

#define C_IN   256
#define C_OUT  512
#define HW     3136      // 56*56
#define NB     32        // batch
#define W_ELEMS (C_OUT*C_IN*9)
#define NQBLK  (W_ELEMS/32)   // 36864 quant blocks

// ---------------- kernel 1: 6-bit fake-quant + repack to Wt[p][co][ci] (bf16) ----------------
__global__ void k_dequant(const float* __restrict__ w, bf16_t* __restrict__ wt) {
    int b = blockIdx.x * blockDim.x + threadIdx.x;
    if (b >= NQBLK) return;
    const float* src = w + (size_t)b * 32;
    float v[32];
    float amax = 0.f;
    #pragma unroll
    for (int i = 0; i < 32; i += 4) {
        float4 t = *reinterpret_cast<const float4*>(src + i);
        v[i] = t.x; v[i+1] = t.y; v[i+2] = t.z; v[i+3] = t.w;
        amax = fmaxf(amax, fmaxf(fmaxf(fabsf(t.x), fabsf(t.y)),
                                 fmaxf(fabsf(t.z), fabsf(t.w))));
    }
    float scale = amax / 31.0f;
    if (scale == 0.f) scale = 1.f;
    #pragma unroll
    for (int i = 0; i < 32; i++) {
        float q = rintf(v[i] / scale);            // jnp.round = RNE = rintf
        q = fminf(31.f, fmaxf(-32.f, q));
        float dq = q * scale;
        int flat = b * 32 + i;                    // flat over OIHW
        int p    = flat % 9;                      // kh*3+kw
        int rest = flat / 9;                      // co*256+ci
        int ci   = rest & 255;
        int co   = rest >> 8;
        wt[((size_t)(p * C_OUT + co) << 8) + ci] = (bf16_t)dq;
    }
}

// ---------------- kernel 2: x NCHW fp32 -> NHWC bf16 (xT[s][ci], s = n*3136+h*56+w) ----------------
__global__ void k_x_nhwc(const float* __restrict__ x, bf16_t* __restrict__ xT) {
    __shared__ float tile[64][65];
    const int n   = blockIdx.z;
    const int cb  = blockIdx.y * 64;     // ci block
    const int hwb = blockIdx.x * 64;     // hw block (3136/64 = 49 exact)
    const int t   = threadIdx.x;

    // read phase: coalesced over hw
    const int col = t & 63;
    const int r0  = t >> 6;              // wave id 0..3
    #pragma unroll
    for (int k = 0; k < 16; k++) {
        int r = r0 * 16 + k;             // ci row 0..63
        tile[r][col] = x[((size_t)(n * C_IN + cb + r)) * HW + hwb + col];
    }
    __syncthreads();

    // write phase: contiguous ci per hw row
    const int j  = t >> 2;               // hw row 0..63
    const int co = (t & 3) * 16;         // ci chunk
    __align__(16) bf16_t vals[16];
    #pragma unroll
    for (int k = 0; k < 16; k++)
        vals[k] = (bf16_t)tile[co + k][j];
    bf16_t* dst = xT + ((size_t)(n * HW + hwb + j)) * C_IN + cb + co;
    *reinterpret_cast<uint4*>(dst)     = *reinterpret_cast<uint4*>(&vals[0]);
    *reinterpret_cast<uint4*>(dst + 8) = *reinterpret_cast<uint4*>(&vals[8]);
}

// ---------------- kernel 3: implicit-GEMM conv, bf16 MFMA ----------------
// M = co (512, 4 blocks of 128), N = s (100352, 784 blocks of 128), K = 9 pos x 256 ci
#define BM 128
#define BN 128
#define LDP 40          // 32 + 8 pad (row = 80 B, 16B-aligned, <=2-way bank alias = free)
#define NSTEPS 72       // 9 positions * 8 ci-chunks of 32

__global__ __launch_bounds__(256, 2) void k_conv_gemm(
    const bf16_t* __restrict__ xT, const bf16_t* __restrict__ wt,
    const float* __restrict__ bias, float* __restrict__ out)
{
    __shared__ __align__(16) bf16_t As[BM][LDP];
    __shared__ __align__(16) bf16_t Bs[BN][LDP];

    const int tid  = threadIdx.x;
    const int lane = tid & 63;
    const int wid  = tid >> 6;
    const int wr   = wid >> 1, wc = wid & 1;   // 2x2 waves, each 64x64

    const int s0  = blockIdx.x * BN;
    const int co0 = blockIdx.y * BM;

    // staging: thread owns one row (co for A, s-col for B), one 16-elem half of K=32
    const int srow  = tid >> 1;        // 0..127
    const int shalf = tid & 1;         // 0/1

    // decode my B column once (hoisted)
    const int cg   = s0 + srow;
    const int nimg = cg / HW;
    const int hwp  = cg - nimg * HW;
    const int hh0  = hwp / 56;
    const int ww0  = hwp - hh0 * 56;
    const size_t ximg = (size_t)nimg * HW * C_IN;

    f32x4 acc[4][4];
    #pragma unroll
    for (int m = 0; m < 4; m++)
        #pragma unroll
        for (int n = 0; n < 4; n++)
            acc[m][n] = f32x4{0.f, 0.f, 0.f, 0.f};

    uint4 ra0, ra1, rb0, rb1;

    auto load_step = [&](int ks) {
        const int p  = ks >> 3;                  // kernel position 0..8
        const int kc = (ks & 7) * 32;            // ci chunk base
        // A: Wt[p][co0+srow][kc + shalf*8 ...]
        const bf16_t* ap = wt + ((size_t)(p * C_OUT + co0 + srow) << 8) + kc + shalf * 8;
        ra0 = *reinterpret_cast<const uint4*>(ap);
        ra1 = *reinterpret_cast<const uint4*>(ap + 16);
        // B: shifted pixel with zero padding
        const int dh = p / 3 - 1, dw = p % 3 - 1;
        const int hh = hh0 + dh, ww = ww0 + dw;
        const bool valid = ((unsigned)hh < 56u) && ((unsigned)ww < 56u);
        if (valid) {
            const bf16_t* bp = xT + ximg + ((size_t)(hh * 56 + ww) << 8) + kc + shalf * 8;
            rb0 = *reinterpret_cast<const uint4*>(bp);
            rb1 = *reinterpret_cast<const uint4*>(bp + 16);
        } else {
            rb0 = make_uint4(0, 0, 0, 0);
            rb1 = make_uint4(0, 0, 0, 0);
        }
    };

    load_step(0);

    for (int ks = 0; ks < NSTEPS; ++ks) {
        __syncthreads();   // previous compute done, LDS free
        *reinterpret_cast<uint4*>(&As[srow][shalf * 8])      = ra0;
        *reinterpret_cast<uint4*>(&As[srow][shalf * 8 + 16]) = ra1;
        *reinterpret_cast<uint4*>(&Bs[srow][shalf * 8])      = rb0;
        *reinterpret_cast<uint4*>(&Bs[srow][shalf * 8 + 16]) = rb1;
        __syncthreads();   // LDS ready
        if (ks + 1 < NSTEPS) load_step(ks + 1);   // prefetch next tile into regs

        bf16x8 aF[4], bF[4];
        #pragma unroll
        for (int m = 0; m < 4; m++)
            aF[m] = *reinterpret_cast<const bf16x8*>(&As[wr * 64 + m * 16 + (lane & 15)][(lane >> 4) * 8]);
        #pragma unroll
        for (int n = 0; n < 4; n++)
            bF[n] = *reinterpret_cast<const bf16x8*>(&Bs[wc * 64 + n * 16 + (lane & 15)][(lane >> 4) * 8]);

        #pragma unroll
        for (int m = 0; m < 4; m++)
            #pragma unroll
            for (int n = 0; n < 4; n++)
                acc[m][n] = __builtin_amdgcn_mfma_f32_16x16x32_bf16(aF[m], bF[n], acc[m][n], 0, 0, 0);
    }

    // epilogue: D row = co-in-tile = 4*(lane>>4)+i, col = s-in-tile = lane&15  (m89/m91 layout)
    int sd_n[4], sd_hw[4];
    #pragma unroll
    for (int n = 0; n < 4; n++) {
        int s = s0 + wc * 64 + n * 16 + (lane & 15);
        sd_n[n]  = s / HW;
        sd_hw[n] = s - sd_n[n] * HW;
    }
    #pragma unroll
    for (int m = 0; m < 4; m++) {
        int cob = co0 + wr * 64 + m * 16 + ((lane >> 4) << 2);
        #pragma unroll
        for (int i = 0; i < 4; i++) {
            int co = cob + i;
            float bv = bias[co];
            #pragma unroll
            for (int n = 0; n < 4; n++) {
                out[((size_t)(sd_n[n] * C_OUT + co)) * HW + sd_hw[n]] = acc[m][n][i] + bv;
            }
        }
    }
}

extern "C" void kernel_launch(void* const* d_in, const int* in_sizes, int n_in,
                              void* d_out, int out_size, void* d_ws, size_t ws_size,
                              hipStream_t stream) {
    const float* x    = (const float*)d_in[0];
    const float* w    = (const float*)d_in[1];
    const float* bias = (const float*)d_in[2];
    float* out = (float*)d_out;

    // workspace layout: xT (bf16 NHWC, 51.4 MB) then Wt (bf16 [9][512][256], 2.4 MB)
    bf16_t* xT = (bf16_t*)d_ws;
    bf16_t* wt = (bf16_t*)((char*)d_ws + (size_t)NB * HW * C_IN * 2);

    k_dequant<<<dim3((NQBLK + 255) / 256), dim3(256), 0, stream>>>(w, wt);
    k_x_nhwc<<<dim3(49, 4, 32), dim3(256), 0, stream>>>(x, xT);
    k_conv_gemm<<<dim3(784, 4), dim3(256), 0, stream>>>(xT, wt, bias, out);
}

// Round 2
// 330.136 us; speedup vs baseline: 1.1496x; 1.1496x over previous
//
#include <hip/hip_runtime.h>
#include <hip/hip_bf16.h>

typedef __bf16 bf16_t;
typedef __attribute__((ext_vector_type(8))) __bf16 bf16x8;
typedef __attribute__((ext_vector_type(4))) float f32x4;

#define C_IN   256
#define C_OUT  512
#define HW     3136      // 56*56
#define NB     32        // batch
#define HP     58        // 56 + 2 halo
#define W_ELEMS (C_OUT*C_IN*9)
#define NQBLK  (W_ELEMS/32)   // 36864 quant blocks

// ---- async global->LDS, 16B per lane (dest = wave-uniform base + lane*16) ----
typedef const __attribute__((address_space(1))) unsigned int gu32;
typedef __attribute__((address_space(3))) unsigned int lu32;
__device__ __forceinline__ void gl16(const void* g, void* l) {
    __builtin_amdgcn_global_load_lds((gu32*)g, (lu32*)l, 16, 0, 0);
}

// ---------------- kernel 1: 6-bit fake-quant + repack to Wt[p][co][ci] (bf16) ----------------
__global__ void k_dequant(const float* __restrict__ w, bf16_t* __restrict__ wt) {
    int b = blockIdx.x * blockDim.x + threadIdx.x;
    if (b >= NQBLK) return;
    const float* src = w + (size_t)b * 32;
    float v[32];
    float amax = 0.f;
    #pragma unroll
    for (int i = 0; i < 32; i += 4) {
        float4 t = *reinterpret_cast<const float4*>(src + i);
        v[i] = t.x; v[i+1] = t.y; v[i+2] = t.z; v[i+3] = t.w;
        amax = fmaxf(amax, fmaxf(fmaxf(fabsf(t.x), fabsf(t.y)),
                                 fmaxf(fabsf(t.z), fabsf(t.w))));
    }
    float scale = amax / 31.0f;
    if (scale == 0.f) scale = 1.f;
    #pragma unroll
    for (int i = 0; i < 32; i++) {
        float q = rintf(v[i] / scale);            // jnp.round = RNE = rintf
        q = fminf(31.f, fmaxf(-32.f, q));
        float dq = q * scale;
        int flat = b * 32 + i;                    // flat over OIHW
        int p    = flat % 9;                      // kh*3+kw
        int rest = flat / 9;                      // co*256+ci
        int ci   = rest & 255;
        int co   = rest >> 8;
        wt[((size_t)(p * C_OUT + co) << 8) + ci] = (bf16_t)dq;
    }
}

// ---------------- kernel 1b: zero the 1-pixel halo ring of xT ----------------
__global__ void k_halo_zero(bf16_t* __restrict__ xT) {
    int idx = blockIdx.x * 256 + threadIdx.x;     // 32 imgs * 228 halo px * 32 chunks
    if (idx >= NB * 228 * 32) return;
    int c8 = idx & 31;
    int t  = idx >> 5;
    int p  = t % 228;
    int n  = t / 228;
    int hh, ww;
    if      (p < 58)  { hh = 0;           ww = p; }
    else if (p < 116) { hh = 57;          ww = p - 58; }
    else if (p < 172) { hh = p - 116 + 1; ww = 0; }
    else              { hh = p - 172 + 1; ww = 57; }
    size_t e = (((size_t)n * HP + hh) * HP + ww) * C_IN + c8 * 8;
    *reinterpret_cast<uint4*>(xT + e) = make_uint4(0, 0, 0, 0);
}

// ------- kernel 2: x NCHW fp32 -> halo-padded NHWC bf16 (xT[n][58][58][ci]) -------
__global__ void k_x_nhwc(const float* __restrict__ x, bf16_t* __restrict__ xT) {
    __shared__ float tile[64][65];
    const int n   = blockIdx.z;
    const int cb  = blockIdx.y * 64;     // ci block
    const int hwb = blockIdx.x * 64;     // hw block (3136/64 = 49 exact)
    const int t   = threadIdx.x;

    const int col = t & 63;
    const int r0  = t >> 6;
    #pragma unroll
    for (int k = 0; k < 16; k++) {
        int r = r0 * 16 + k;
        tile[r][col] = x[((size_t)(n * C_IN + cb + r)) * HW + hwb + col];
    }
    __syncthreads();

    const int j  = t >> 2;               // hw row 0..63
    const int co = (t & 3) * 16;         // ci chunk
    const int hw = hwb + j;
    const int hh = hw / 56, ww = hw - hh * 56;
    __align__(16) bf16_t vals[16];
    #pragma unroll
    for (int k = 0; k < 16; k++)
        vals[k] = (bf16_t)tile[co + k][j];
    bf16_t* dst = xT + (((size_t)n * HP + hh + 1) * HP + (ww + 1)) * C_IN + cb + co;
    *reinterpret_cast<uint4*>(dst)     = *reinterpret_cast<uint4*>(&vals[0]);
    *reinterpret_cast<uint4*>(dst + 8) = *reinterpret_cast<uint4*>(&vals[8]);
}

// ---------------- kernel 3: implicit-GEMM conv, bf16 MFMA ----------------
// M = co (512, 4 blocks of 128), N = s (100352, 784 blocks of 128), K = 9 pos x 256 ci
// global_load_lds staging, linear LDS [128][32] (conflict-free reads),
// 2-phase double buffer (stage t+1 before compute t), XCD-aware swizzle.
#define BM 128
#define BN 128
#define BK 32
#define NSTEPS 72       // 9 positions * 8 ci-chunks of 32
#define NWG 3136        // 784 s-blocks * 4 co-blocks

__global__ __launch_bounds__(256, 4) void k_conv_gemm(
    const bf16_t* __restrict__ xT, const bf16_t* __restrict__ wt,
    const float* __restrict__ bias, float* __restrict__ out)
{
    __shared__ __align__(16) bf16_t As[2][BM][BK];   // 2 x 8 KB
    __shared__ __align__(16) bf16_t Bs[2][BN][BK];   // 2 x 8 KB

    const int tid  = threadIdx.x;
    const int lane = tid & 63;
    const int wid  = tid >> 6;
    const int wr   = wid >> 1, wc = wid & 1;     // 2x2 waves, each 64x64

    // XCD swizzle: each XCD gets 98 contiguous s-blocks, co-fastest within
    const int orig = blockIdx.x;
    const int wgid = (orig & 7) * (NWG / 8) + (orig >> 3);
    const int coblk = wgid & 3;
    const int sblk  = wgid >> 2;
    const int s0  = sblk * BN;
    const int co0 = coblk * BM;

    // staging geometry: wave w, issue j covers rows [(w*2+j)*16, +16)
    // lane l -> row offset l>>2, 16B chunk l&3
    const int wid2 = wid * 2;
    const int rofs = lane >> 2;
    const int cofs = (lane & 3) * 8;             // element offset within K=32 row

    const bf16_t* pA0 = wt + ((size_t)(co0 + wid2 * 16 + rofs) << 8) + cofs;
    const bf16_t* pA1 = pA0 + (16 << 8);

    // per-thread B pixel bases (halo layout), hoisted
    const bf16_t* pB[2];
    #pragma unroll
    for (int j = 0; j < 2; j++) {
        int s  = s0 + (wid2 + j) * 16 + rofs;
        int n  = s / HW;
        int hw = s - n * HW;
        int hh = hw / 56, ww = hw - hh * 56;
        pB[j] = xT + (((size_t)n * HP + hh + 1) * HP + (ww + 1)) * C_IN + cofs;
    }

    f32x4 acc[4][4];
    #pragma unroll
    for (int m = 0; m < 4; m++)
        #pragma unroll
        for (int n = 0; n < 4; n++)
            acc[m][n] = f32x4{0.f, 0.f, 0.f, 0.f};

    auto stage = [&](int buf, int ks) {
        const int p  = ks >> 3;
        const int kc = (ks & 7) << 5;
        const int dh = p / 3 - 1, dw = p % 3 - 1;
        const int boff = (dh * HP + dw) * C_IN + kc;
        const size_t aoff = (size_t)p * (C_OUT << 8) + kc;
        gl16(pA0 + aoff,   &As[buf][wid2 * 16][0]);
        gl16(pA1 + aoff,   &As[buf][(wid2 + 1) * 16][0]);
        gl16(pB[0] + boff, &Bs[buf][wid2 * 16][0]);
        gl16(pB[1] + boff, &Bs[buf][(wid2 + 1) * 16][0]);
    };

    stage(0, 0);
    __syncthreads();               // vmcnt(0) drain + barrier: buf0 ready

    int cur = 0;
    for (int ks = 0; ks < NSTEPS; ++ks) {
        if (ks + 1 < NSTEPS) stage(cur ^ 1, ks + 1);   // issue next tile first

        bf16x8 aF[4], bF[4];
        #pragma unroll
        for (int m = 0; m < 4; m++)
            aF[m] = *reinterpret_cast<const bf16x8*>(
                &As[cur][wr * 64 + m * 16 + (lane & 15)][(lane >> 4) * 8]);
        #pragma unroll
        for (int n = 0; n < 4; n++)
            bF[n] = *reinterpret_cast<const bf16x8*>(
                &Bs[cur][wc * 64 + n * 16 + (lane & 15)][(lane >> 4) * 8]);

        #pragma unroll
        for (int m = 0; m < 4; m++)
            #pragma unroll
            for (int n = 0; n < 4; n++)
                acc[m][n] = __builtin_amdgcn_mfma_f32_16x16x32_bf16(aF[m], bF[n], acc[m][n], 0, 0, 0);

        __syncthreads();           // drains vmcnt(0): next buf staged; readers done
        cur ^= 1;
    }

    // epilogue: D row = co-in-tile = 4*(lane>>4)+i, col = s-in-tile = lane&15
    int sd_n[4], sd_hw[4];
    #pragma unroll
    for (int n = 0; n < 4; n++) {
        int s = s0 + wc * 64 + n * 16 + (lane & 15);
        sd_n[n]  = s / HW;
        sd_hw[n] = s - sd_n[n] * HW;
    }
    #pragma unroll
    for (int m = 0; m < 4; m++) {
        int cob = co0 + wr * 64 + m * 16 + ((lane >> 4) << 2);
        #pragma unroll
        for (int i = 0; i < 4; i++) {
            int co = cob + i;
            float bv = bias[co];
            #pragma unroll
            for (int n = 0; n < 4; n++) {
                out[((size_t)(sd_n[n] * C_OUT + co)) * HW + sd_hw[n]] = acc[m][n][i] + bv;
            }
        }
    }
}

extern "C" void kernel_launch(void* const* d_in, const int* in_sizes, int n_in,
                              void* d_out, int out_size, void* d_ws, size_t ws_size,
                              hipStream_t stream) {
    const float* x    = (const float*)d_in[0];
    const float* w    = (const float*)d_in[1];
    const float* bias = (const float*)d_in[2];
    float* out = (float*)d_out;

    // workspace: xT halo-padded NHWC bf16 (32*58*58*256*2 = 55.1 MB) then Wt (2.4 MB)
    bf16_t* xT = (bf16_t*)d_ws;
    bf16_t* wt = (bf16_t*)((char*)d_ws + (size_t)NB * HP * HP * C_IN * 2);

    k_halo_zero<<<dim3((NB * 228 * 32 + 255) / 256), dim3(256), 0, stream>>>(xT);
    k_x_nhwc<<<dim3(49, 4, NB), dim3(256), 0, stream>>>(x, xT);
    k_dequant<<<dim3((NQBLK + 255) / 256), dim3(256), 0, stream>>>(w, wt);
    k_conv_gemm<<<dim3(NWG), dim3(256), 0, stream>>>(xT, wt, bias, out);
}

// Round 3
// 306.418 us; speedup vs baseline: 1.2386x; 1.0774x over previous
//
#include <hip/hip_runtime.h>
#include <hip/hip_bf16.h>

typedef __bf16 bf16_t;
typedef __attribute__((ext_vector_type(8))) __bf16 bf16x8;
typedef __attribute__((ext_vector_type(4))) float f32x4;

#define C_IN   256
#define C_OUT  512
#define HW     3136      // 56*56
#define NB     32        // batch
#define HP     58        // 56 + 2 halo
#define NQBLK  36864     // (512*256*9)/32 quant blocks
#define NT     36        // K-tiles: 9 positions * 4 ci-chunks of 64
#define NWG    784       // 392 s-blocks * 2 co-blocks

// ---- async global->LDS, 16B per lane (dest = wave-uniform base + lane*16) ----
typedef const __attribute__((address_space(1))) unsigned int gu32;
typedef __attribute__((address_space(3))) unsigned int lu32;
__device__ __forceinline__ void gl16(const void* g, void* l) {
    __builtin_amdgcn_global_load_lds((gu32*)g, (lu32*)l, 16, 0, 0);
}
#define BAR()    __builtin_amdgcn_s_barrier()
#define PRIO(x)  __builtin_amdgcn_s_setprio(x)
#define SCHED0() __builtin_amdgcn_sched_barrier(0)

// ---------------- kernel 1: 6-bit fake-quant + repack to Wt[p][co][ci] (bf16) ----------------
__global__ void k_dequant(const float* __restrict__ w, bf16_t* __restrict__ wt) {
    int b = blockIdx.x * blockDim.x + threadIdx.x;
    if (b >= NQBLK) return;
    const float* src = w + (size_t)b * 32;
    float v[32];
    float amax = 0.f;
    #pragma unroll
    for (int i = 0; i < 32; i += 4) {
        float4 t = *reinterpret_cast<const float4*>(src + i);
        v[i] = t.x; v[i+1] = t.y; v[i+2] = t.z; v[i+3] = t.w;
        amax = fmaxf(amax, fmaxf(fmaxf(fabsf(t.x), fabsf(t.y)),
                                 fmaxf(fabsf(t.z), fabsf(t.w))));
    }
    float scale = amax / 31.0f;
    if (scale == 0.f) scale = 1.f;
    #pragma unroll
    for (int i = 0; i < 32; i++) {
        float q = rintf(v[i] / scale);            // jnp.round = RNE = rintf
        q = fminf(31.f, fmaxf(-32.f, q));
        float dq = q * scale;
        int flat = b * 32 + i;                    // flat over OIHW
        int p    = flat % 9;
        int rest = flat / 9;
        int ci   = rest & 255;
        int co   = rest >> 8;
        wt[((size_t)(p * C_OUT + co) << 8) + ci] = (bf16_t)dq;
    }
}

// ---------------- kernel 1b: zero the 1-pixel halo ring of xT ----------------
__global__ void k_halo_zero(bf16_t* __restrict__ xT) {
    int idx = blockIdx.x * 256 + threadIdx.x;
    if (idx >= NB * 228 * 32) return;
    int c8 = idx & 31;
    int t  = idx >> 5;
    int p  = t % 228;
    int n  = t / 228;
    int hh, ww;
    if      (p < 58)  { hh = 0;           ww = p; }
    else if (p < 116) { hh = 57;          ww = p - 58; }
    else if (p < 172) { hh = p - 116 + 1; ww = 0; }
    else              { hh = p - 172 + 1; ww = 57; }
    size_t e = (((size_t)n * HP + hh) * HP + ww) * C_IN + c8 * 8;
    *reinterpret_cast<uint4*>(xT + e) = make_uint4(0, 0, 0, 0);
}

// ------- kernel 2: x NCHW fp32 -> halo-padded NHWC bf16 (xT[n][58][58][ci]) -------
__global__ void k_x_nhwc(const float* __restrict__ x, bf16_t* __restrict__ xT) {
    __shared__ float tile[64][65];
    const int n   = blockIdx.z;
    const int cb  = blockIdx.y * 64;
    const int hwb = blockIdx.x * 64;
    const int t   = threadIdx.x;

    const int col = t & 63;
    const int r0  = t >> 6;
    #pragma unroll
    for (int k = 0; k < 16; k++) {
        int r = r0 * 16 + k;
        tile[r][col] = x[((size_t)(n * C_IN + cb + r)) * HW + hwb + col];
    }
    __syncthreads();

    const int j  = t >> 2;
    const int co = (t & 3) * 16;
    const int hw = hwb + j;
    const int hh = hw / 56, ww = hw - hh * 56;
    __align__(16) bf16_t vals[16];
    #pragma unroll
    for (int k = 0; k < 16; k++)
        vals[k] = (bf16_t)tile[co + k][j];
    bf16_t* dst = xT + (((size_t)n * HP + hh + 1) * HP + (ww + 1)) * C_IN + cb + co;
    *reinterpret_cast<uint4*>(dst)     = *reinterpret_cast<uint4*>(&vals[0]);
    *reinterpret_cast<uint4*>(dst + 8) = *reinterpret_cast<uint4*>(&vals[8]);
}

// ---------------- kernel 3: implicit-GEMM conv, 256x256 8-phase template ----------------
// M = co (512 -> 2 blocks of 256), N = s (100352 -> 392 blocks of 256), K = 9 pos x 256 ci.
// 8 waves as 2(M) x 4(N); per-wave output 128x64 = acc[8][4] f32x4.
// LDS: 2 dbuf x (A[256][64] + B[256][64]) bf16 = 128 KiB. Rows = 128 B.
// XOR swizzle: 16B-chunk ^= (row & 7); applied on global SOURCE (gl16 dest linear) and on ds_read.
//
// Stage ledger (1 half = 128 rows = 2 gl16/thread; buf(t)=t&1):
//   slots for tile T: A-lo @ (T-2).P4 | A-hi @ (T-1).P1 | B-lo @ (T-1).P2 | B-hi @ (T-1).P3
//   t.P1..P3 write buf(t^1)  -> never read during tile t: safe.
//   t.P4 writes buf(t) A-lo  -> all reads of buf(t) retired by P3's end barrier: safe.
//   wait: vmcnt(2) at each t.P4 (only P4's own 2 loads outstanding) => tile t+1 fully landed.
//   tail: when P4 stage skipped (t+2>=NT), vmcnt(0) so t+1's B-hi is covered.
__global__ __launch_bounds__(512, 2) void k_conv_gemm(
    const bf16_t* __restrict__ xT, const bf16_t* __restrict__ wt,
    const float* __restrict__ bias, float* __restrict__ out)
{
    __shared__ __align__(16) bf16_t As[2][256][64];   // 64 KB
    __shared__ __align__(16) bf16_t Bs[2][256][64];   // 64 KB

    const int tid  = threadIdx.x;
    const int lane = tid & 63;
    const int wid  = tid >> 6;
    const int wr   = wid >> 2, wc = wid & 3;   // 2x4 waves, each 128x64 output

    // XCD bijective swizzle: 784 = 8 * 98; co-fastest within an XCD chunk
    const int orig = blockIdx.x;
    const int wgid = (orig & 7) * (NWG / 8) + (orig >> 3);
    const int co0  = (wgid & 1) * 256;
    const int s0   = (wgid >> 1) * 256;

    // ---- staging geometry: thread t covers row (t>>3) of each 64-row issue, chunk (t&7)
    const int trow = tid >> 3;
    const int lc   = (tid & 7) ^ (trow & 7);   // logical chunk for pre-swizzled source
    const bf16_t* pA[2][2];
    const bf16_t* pB[2][2];
    #pragma unroll
    for (int h = 0; h < 2; h++)
        #pragma unroll
        for (int j = 0; j < 2; j++) {
            int r = h * 128 + j * 64 + trow;
            pA[h][j] = wt + ((size_t)(co0 + r) << 8) + lc * 8;
            int s  = s0 + r;
            int n  = s / HW;
            int hw = s - n * HW;
            int hh = hw / 56, ww = hw - hh * 56;
            pB[h][j] = xT + (((size_t)n * HP + hh + 1) * HP + (ww + 1)) * C_IN + lc * 8;
        }

    // wave-uniform LDS dest base (HW writes lane*16 past it)
    bf16_t* dA = &As[0][0][0] + wid * 512;     // wid*8 rows * 64
    bf16_t* dB = &Bs[0][0][0] + wid * 512;

    auto stageA = [&](int buf, int kt, int h) {
        const int p = kt >> 2;
        const size_t off = (size_t)p * (C_OUT << 8) + ((kt & 3) << 6);
        #pragma unroll
        for (int j = 0; j < 2; j++)
            gl16(pA[h][j] + off, dA + buf * 16384 + (h * 128 + j * 64) * 64);
    };
    auto stageB = [&](int buf, int kt, int h) {
        const int p = kt >> 2;
        const int off = (p / 3 - 1) * (HP * C_IN) + (p % 3 - 1) * C_IN + ((kt & 3) << 6);
        #pragma unroll
        for (int j = 0; j < 2; j++)
            gl16(pB[h][j] + off, dB + buf * 16384 + (h * 128 + j * 64) * 64);
    };

    // ---- prologue: tile0 all 4 halves + tile1 A-lo; drain tile0 (vmcnt(2)) ----
    stageA(0, 0, 0); stageA(0, 0, 1); stageB(0, 0, 0); stageB(0, 0, 1);
    stageA(1, 1, 0);
    asm volatile("s_waitcnt vmcnt(2)" ::: "memory");
    BAR();

    // ---- fragment-read constants (swizzled chunk, key = row&7 = lane&7) ----
    const int rl   = lane & 15;
    const int pcb0 = (((lane >> 4))     ^ (lane & 7)) * 8;   // k=0 elem offset
    const int pcb1 = ((4 + (lane >> 4)) ^ (lane & 7)) * 8;   // k=1 elem offset

    f32x4 acc[8][4];
    #pragma unroll
    for (int m = 0; m < 8; m++)
        #pragma unroll
        for (int n = 0; n < 4; n++)
            acc[m][n] = f32x4{0.f, 0.f, 0.f, 0.f};

    bf16x8 aF[4][2], bF[2][2], bG[2][2];

    for (int t = 0; t < NT; ++t) {
        const int cur = t & 1;

        // ======== P1: ds_read A(m0-3) + B(n0-1) [12]; stage A-hi(t+1); MFMA Q(m0-3,n0-1)
        #pragma unroll
        for (int m = 0; m < 4; m++) {
            const bf16_t* rp = &As[cur][wr * 128 + m * 16 + rl][0];
            aF[m][0] = *reinterpret_cast<const bf16x8*>(rp + pcb0);
            aF[m][1] = *reinterpret_cast<const bf16x8*>(rp + pcb1);
        }
        #pragma unroll
        for (int n = 0; n < 2; n++) {
            const bf16_t* rp = &Bs[cur][wc * 64 + n * 16 + rl][0];
            bF[n][0] = *reinterpret_cast<const bf16x8*>(rp + pcb0);
            bF[n][1] = *reinterpret_cast<const bf16x8*>(rp + pcb1);
        }
        if (t + 1 < NT) stageA(cur ^ 1, t + 1, 1);
        BAR();
        asm volatile("s_waitcnt lgkmcnt(0)" ::: "memory");
        SCHED0();
        PRIO(1);
        #pragma unroll
        for (int m = 0; m < 4; m++)
            #pragma unroll
            for (int n = 0; n < 2; n++) {
                acc[m][n] = __builtin_amdgcn_mfma_f32_16x16x32_bf16(aF[m][0], bF[n][0], acc[m][n], 0, 0, 0);
                acc[m][n] = __builtin_amdgcn_mfma_f32_16x16x32_bf16(aF[m][1], bF[n][1], acc[m][n], 0, 0, 0);
            }
        PRIO(0);
        BAR();

        // ======== P2: ds_read B(n2-3) [4]; stage B-lo(t+1); MFMA Q(m0-3,n2-3)
        #pragma unroll
        for (int n = 0; n < 2; n++) {
            const bf16_t* rp = &Bs[cur][wc * 64 + (n + 2) * 16 + rl][0];
            bG[n][0] = *reinterpret_cast<const bf16x8*>(rp + pcb0);
            bG[n][1] = *reinterpret_cast<const bf16x8*>(rp + pcb1);
        }
        if (t + 1 < NT) stageB(cur ^ 1, t + 1, 0);
        BAR();
        asm volatile("s_waitcnt lgkmcnt(0)" ::: "memory");
        SCHED0();
        PRIO(1);
        #pragma unroll
        for (int m = 0; m < 4; m++)
            #pragma unroll
            for (int n = 0; n < 2; n++) {
                acc[m][n + 2] = __builtin_amdgcn_mfma_f32_16x16x32_bf16(aF[m][0], bG[n][0], acc[m][n + 2], 0, 0, 0);
                acc[m][n + 2] = __builtin_amdgcn_mfma_f32_16x16x32_bf16(aF[m][1], bG[n][1], acc[m][n + 2], 0, 0, 0);
            }
        PRIO(0);
        BAR();

        // ======== P3: ds_read A(m4-7) [8]; stage B-hi(t+1); MFMA Q(m4-7,n2-3)
        #pragma unroll
        for (int m = 0; m < 4; m++) {
            const bf16_t* rp = &As[cur][wr * 128 + (m + 4) * 16 + rl][0];
            aF[m][0] = *reinterpret_cast<const bf16x8*>(rp + pcb0);
            aF[m][1] = *reinterpret_cast<const bf16x8*>(rp + pcb1);
        }
        if (t + 1 < NT) stageB(cur ^ 1, t + 1, 1);
        BAR();
        asm volatile("s_waitcnt lgkmcnt(0)" ::: "memory");
        SCHED0();
        PRIO(1);
        #pragma unroll
        for (int m = 0; m < 4; m++)
            #pragma unroll
            for (int n = 0; n < 2; n++) {
                acc[m + 4][n + 2] = __builtin_amdgcn_mfma_f32_16x16x32_bf16(aF[m][0], bG[n][0], acc[m + 4][n + 2], 0, 0, 0);
                acc[m + 4][n + 2] = __builtin_amdgcn_mfma_f32_16x16x32_bf16(aF[m][1], bG[n][1], acc[m + 4][n + 2], 0, 0, 0);
            }
        PRIO(0);
        BAR();

        // ======== P4: stage A-lo(t+2); vmcnt(2) [vmcnt(0) at tail]; MFMA Q(m4-7,n0-1)
        if (t + 2 < NT) {
            stageA(cur, t + 2, 0);
            asm volatile("s_waitcnt vmcnt(2)" ::: "memory");
        } else {
            asm volatile("s_waitcnt vmcnt(0)" ::: "memory");
        }
        BAR();
        PRIO(1);
        #pragma unroll
        for (int m = 0; m < 4; m++)
            #pragma unroll
            for (int n = 0; n < 2; n++) {
                acc[m + 4][n] = __builtin_amdgcn_mfma_f32_16x16x32_bf16(aF[m][0], bF[n][0], acc[m + 4][n], 0, 0, 0);
                acc[m + 4][n] = __builtin_amdgcn_mfma_f32_16x16x32_bf16(aF[m][1], bF[n][1], acc[m + 4][n], 0, 0, 0);
            }
        PRIO(0);
        BAR();
    }

    // ---- epilogue: D row(co) = 4*(lane>>4)+i, col(s) = lane&15 ----
    int sd_n[4], sd_hw[4];
    #pragma unroll
    for (int n = 0; n < 4; n++) {
        int s = s0 + wc * 64 + n * 16 + rl;
        sd_n[n]  = s / HW;
        sd_hw[n] = s - sd_n[n] * HW;
    }
    #pragma unroll
    for (int m = 0; m < 8; m++) {
        int cob = co0 + wr * 128 + m * 16 + ((lane >> 4) << 2);
        #pragma unroll
        for (int i = 0; i < 4; i++) {
            int co = cob + i;
            float bv = bias[co];
            #pragma unroll
            for (int n = 0; n < 4; n++) {
                out[((size_t)(sd_n[n] * C_OUT + co)) * HW + sd_hw[n]] = acc[m][n][i] + bv;
            }
        }
    }
}

extern "C" void kernel_launch(void* const* d_in, const int* in_sizes, int n_in,
                              void* d_out, int out_size, void* d_ws, size_t ws_size,
                              hipStream_t stream) {
    const float* x    = (const float*)d_in[0];
    const float* w    = (const float*)d_in[1];
    const float* bias = (const float*)d_in[2];
    float* out = (float*)d_out;

    // workspace: xT halo-padded NHWC bf16 (32*58*58*256*2 = 55.1 MB) then Wt (2.4 MB)
    bf16_t* xT = (bf16_t*)d_ws;
    bf16_t* wt = (bf16_t*)((char*)d_ws + (size_t)NB * HP * HP * C_IN * 2);

    k_halo_zero<<<dim3((NB * 228 * 32 + 255) / 256), dim3(256), 0, stream>>>(xT);
    k_x_nhwc<<<dim3(49, 4, NB), dim3(256), 0, stream>>>(x, xT);
    k_dequant<<<dim3((NQBLK + 255) / 256), dim3(256), 0, stream>>>(w, wt);
    k_conv_gemm<<<dim3(NWG), dim3(512), 0, stream>>>(xT, wt, bias, out);
}